// Round 1
// baseline (392.536 us; speedup 1.0000x reference)
//
#include <hip/hip_runtime.h>
#include <hip/hip_bf16.h>

#define DD 64

// ---------------- degree kernel ----------------
__global__ __launch_bounds__(256) void degree_kernel(
    const int* __restrict__ src, const int* __restrict__ dst,
    float* __restrict__ odeg, float* __restrict__ ideg, int E)
{
    int tid = blockIdx.x * 256 + threadIdx.x;
    if (tid < E) {
        atomicAdd(&odeg[src[tid]], 1.0f);
        atomicAdd(&ideg[dst[tid]], 1.0f);
    }
}

// ---------------- scatter-aggregate kernel ----------------
// one wave (64 lanes) per edge; lane = feature dim
__global__ __launch_bounds__(256) void scatter_kernel(
    const float* __restrict__ x,
    const int* __restrict__ src, const int* __restrict__ dst,
    const float* __restrict__ odeg, const float* __restrict__ ideg,
    float* __restrict__ agg, int E)
{
    int lane = threadIdx.x & 63;
    int e = blockIdx.x * 4 + (threadIdx.x >> 6);
    if (e >= E) return;
    int s = src[e];
    int d = dst[e];
    // prod can never be 0 for a real edge (src has out_deg>=1, dst has in_deg>=1)
    float norm = rsqrtf(odeg[s] * ideg[d]);
    float v = x[(size_t)s * DD + lane] * norm;
    atomicAdd(&agg[(size_t)d * DD + lane], v);
}

// ---------------- FFN kernel (in-place on agg/out) ----------------
// block = 256 threads, processes 64 rows. LDS: tile, W1, W2, H = 64 KB.
__global__ __launch_bounds__(256) void ffn_kernel(
    float* __restrict__ io,
    const float* __restrict__ w1, const float* __restrict__ b1,
    const float* __restrict__ w2, const float* __restrict__ b2, int n)
{
    __shared__ float sW1[64 * 64];
    __shared__ float sW2[64 * 64];
    __shared__ float sT[64 * 64];
    __shared__ float sH[64 * 64];

    int t = threadIdx.x;
    int row0 = blockIdx.x * 64;

    // load weights (coalesced, 16 elems/thread)
    for (int i = 0; i < 16; ++i) {
        sW1[t + i * 256] = w1[t + i * 256];
        sW2[t + i * 256] = w2[t + i * 256];
    }
    // load row tile
    for (int i = 0; i < 16; ++i) {
        int idx = t + i * 256;
        int r = idx >> 6;
        int gr = row0 + r;
        sT[idx] = (gr < n) ? io[(size_t)gr * 64 + (idx & 63)] : 0.0f;
    }
    __syncthreads();

    int c = t & 63;              // lane -> output column
    int rbase = (t >> 6) * 16;   // wave -> 16-row chunk

    // GEMM1 + exact GELU
    float bias1 = b1[c];
    for (int i = 0; i < 16; ++i) {
        int r = rbase + i;
        float acc = bias1;
        #pragma unroll
        for (int k = 0; k < 64; ++k)
            acc = fmaf(sT[r * 64 + k], sW1[k * 64 + c], acc);
        sH[r * 64 + c] = 0.5f * acc * (1.0f + erff(acc * 0.70710678f));
    }
    __syncthreads();

    // GEMM2 + store
    float bias2 = b2[c];
    for (int i = 0; i < 16; ++i) {
        int r = rbase + i;
        float acc = bias2;
        #pragma unroll
        for (int k = 0; k < 64; ++k)
            acc = fmaf(sH[r * 64 + k], sW2[k * 64 + c], acc);
        int gr = row0 + r;
        if (gr < n) io[(size_t)gr * 64 + c] = acc;
    }
}

extern "C" void kernel_launch(void* const* d_in, const int* in_sizes, int n_in,
                              void* d_out, int out_size, void* d_ws, size_t ws_size,
                              hipStream_t stream)
{
    const float* x    = (const float*)d_in[0];
    const int*   esrc = (const int*)d_in[1];
    const int*   edst = (const int*)d_in[2];
    const float* w1   = (const float*)d_in[3];
    const float* b1   = (const float*)d_in[4];
    const float* w2   = (const float*)d_in[5];
    const float* b2   = (const float*)d_in[6];
    float* out = (float*)d_out;

    int N = in_sizes[0] / DD;   // 50000
    int E = in_sizes[1];        // 800000

    float* odeg = (float*)d_ws;
    float* ideg = odeg + N;

    // zero degree scratch and agg buffer (d_out doubles as agg)
    hipMemsetAsync(d_ws, 0, (size_t)2 * N * sizeof(float), stream);
    hipMemsetAsync(d_out, 0, (size_t)N * DD * sizeof(float), stream);

    degree_kernel<<<(E + 255) / 256, 256, 0, stream>>>(esrc, edst, odeg, ideg, E);
    scatter_kernel<<<(E + 3) / 4, 256, 0, stream>>>(x, esrc, edst, odeg, ideg, out, E);
    ffn_kernel<<<(N + 63) / 64, 256, 0, stream>>>(out, w1, b1, w2, b2, N);
}

// Round 2
// 378.038 us; speedup vs baseline: 1.0384x; 1.0384x over previous
//
#include <hip/hip_runtime.h>
#include <hip/hip_bf16.h>
#include <math.h>

#define DD 64

// ---------------- degree kernel (int degrees) ----------------
__global__ __launch_bounds__(256) void degree_kernel(
    const int* __restrict__ src, const int* __restrict__ dst,
    int* __restrict__ odeg, int* __restrict__ ideg, int E)
{
    int e = blockIdx.x * 256 + threadIdx.x;
    if (e < E) {
        atomicAdd(&odeg[src[e]], 1);
        atomicAdd(&ideg[dst[e]], 1);
    }
}

// ---------------- scan kernel ----------------
// single block, 1024 threads: exclusive prefix sum of ideg -> offs,
// and rs_odeg[i] = rsqrt(out_deg[i]) precompute.
__global__ __launch_bounds__(1024) void scan_kernel(
    const int* __restrict__ ideg, const int* __restrict__ odeg,
    int* __restrict__ offs, float* __restrict__ rs_odeg, int n)
{
    __shared__ int wsum[16];
    __shared__ int s_carry;
    int t = threadIdx.x;
    int lane = t & 63, wid = t >> 6;
    if (t == 0) s_carry = 0;
    __syncthreads();
    for (int base = 0; base < n; base += 1024) {
        int i = base + t;
        int v = (i < n) ? ideg[i] : 0;
        int sv = v;
        #pragma unroll
        for (int d = 1; d < 64; d <<= 1) {
            int u = __shfl_up(sv, d, 64);
            if (lane >= d) sv += u;
        }
        if (lane == 63) wsum[wid] = sv;
        __syncthreads();
        if (wid == 0) {
            int wv = (lane < 16) ? wsum[lane] : 0;
            #pragma unroll
            for (int d = 1; d < 16; d <<= 1) {
                int u = __shfl_up(wv, d, 64);
                if (lane >= d) wv += u;
            }
            if (lane < 16) wsum[lane] = wv;
        }
        __syncthreads();
        int carry = s_carry;
        int woff = (wid > 0) ? wsum[wid - 1] : 0;
        if (i < n) {
            offs[i] = carry + woff + (sv - v);      // exclusive prefix
            rs_odeg[i] = rsqrtf((float)odeg[i]);    // inf only for never-src nodes
        }
        __syncthreads();
        if (t == 1023) s_carry = carry + wsum[15];
        __syncthreads();
    }
}

// ---------------- bucket-fill kernel ----------------
// offs[d] is exclusive start; atomic post-increment turns it into inclusive end.
__global__ __launch_bounds__(256) void bucket_kernel(
    const int* __restrict__ src, const int* __restrict__ dst,
    int* __restrict__ offs, int* __restrict__ sorted_src, int E)
{
    int e = blockIdx.x * 256 + threadIdx.x;
    if (e < E) {
        int pos = atomicAdd(&offs[dst[e]], 1);
        sorted_src[pos] = src[e];
    }
}

// ---------------- gather kernel ----------------
// one wave per dst node; lane = feature. After bucket fill:
//   beg(d) = (d==0) ? 0 : offs[d-1],  end(d) = offs[d]
__global__ __launch_bounds__(256) void gather_kernel(
    const float* __restrict__ x,
    const int* __restrict__ sorted_src,
    const int* __restrict__ offs,
    const float* __restrict__ rs_odeg,
    const int* __restrict__ ideg,
    float* __restrict__ out, int N)
{
    int lane = threadIdx.x & 63;
    int d = blockIdx.x * 4 + (threadIdx.x >> 6);
    if (d >= N) return;
    int end = offs[d];
    int beg = (d == 0) ? 0 : offs[d - 1];
    float acc = 0.0f;
    int j = beg;
    for (; j + 1 < end; j += 2) {
        int s0 = sorted_src[j];
        int s1 = sorted_src[j + 1];
        float w0 = rs_odeg[s0];
        float w1 = rs_odeg[s1];
        float x0 = x[(size_t)s0 * DD + lane];
        float x1 = x[(size_t)s1 * DD + lane];
        acc = fmaf(x0, w0, acc);
        acc = fmaf(x1, w1, acc);
    }
    if (j < end) {
        int s = sorted_src[j];
        acc = fmaf(x[(size_t)s * DD + lane], rs_odeg[s], acc);
    }
    float nd = (end > beg) ? rsqrtf((float)ideg[d]) : 0.0f;
    out[(size_t)d * DD + lane] = acc * nd;
}

// ---------------- FFN kernel ----------------
// one wave per block, thread-per-row, 64 rows/block. Weights via wave-uniform
// loads (-> s_load, scalar cache). LDS row buffer stride 68 (b128-aligned, 2-way
// bank alias = free). In-place on io.
__global__ __launch_bounds__(64) void ffn_kernel(
    float* __restrict__ io,
    const float* __restrict__ w1, const float* __restrict__ b1,
    const float* __restrict__ w2, const float* __restrict__ b2, int n)
{
    __shared__ float sT[64 * 68];
    int t = threadIdx.x;           // 0..63
    int row0 = blockIdx.x * 64;

    // stage 64 rows, coalesced: thread t loads column t of each row
    for (int i = 0; i < 64; ++i) {
        int gr = row0 + i;
        sT[i * 68 + t] = (gr < n) ? io[(size_t)gr * DD + t] : 0.0f;
    }
    __syncthreads();

    // ---- GEMM1: h = row . W1 + b1 ----
    float acc[64];
    #pragma unroll
    for (int c = 0; c < 64; ++c) acc[c] = b1[c];
    for (int k = 0; k < 64; ++k) {
        float r = sT[t * 68 + k];
        #pragma unroll
        for (int c = 0; c < 64; ++c)
            acc[c] = fmaf(r, w1[k * 64 + c], acc[c]);
    }
    // exact GELU, write h into own LDS row (no cross-thread -> no barrier)
    #pragma unroll
    for (int c = 0; c < 64; ++c) {
        float v = acc[c];
        v = 0.5f * v * (1.0f + erff(v * 0.70710678118654752f));
        sT[t * 68 + c] = v;
    }

    // ---- GEMM2: out = h . W2 + b2 ----
    #pragma unroll
    for (int c = 0; c < 64; ++c) acc[c] = b2[c];
    for (int k = 0; k < 64; ++k) {
        float hk = sT[t * 68 + k];
        #pragma unroll
        for (int c = 0; c < 64; ++c)
            acc[c] = fmaf(hk, w2[k * 64 + c], acc[c]);
    }
    #pragma unroll
    for (int c = 0; c < 64; ++c) sT[t * 68 + c] = acc[c];
    __syncthreads();

    // coalesced store: thread t stores column t of each row
    for (int i = 0; i < 64; ++i) {
        int gr = row0 + i;
        if (gr < n) io[(size_t)gr * DD + t] = sT[i * 68 + t];
    }
}

extern "C" void kernel_launch(void* const* d_in, const int* in_sizes, int n_in,
                              void* d_out, int out_size, void* d_ws, size_t ws_size,
                              hipStream_t stream)
{
    const float* x    = (const float*)d_in[0];
    const int*   esrc = (const int*)d_in[1];
    const int*   edst = (const int*)d_in[2];
    const float* w1   = (const float*)d_in[3];
    const float* b1   = (const float*)d_in[4];
    const float* w2   = (const float*)d_in[5];
    const float* b2   = (const float*)d_in[6];
    float* out = (float*)d_out;

    int N = in_sizes[0] / DD;   // 50000
    int E = in_sizes[1];        // 800000

    // workspace layout (ints)
    int*   ideg       = (int*)d_ws;          // N
    int*   odeg       = ideg + N;            // N
    int*   offs       = odeg + N;            // N
    float* rs_odeg    = (float*)(offs + N);  // N
    int*   sorted_src = (int*)(rs_odeg + N); // E

    // zero the degree arrays only
    hipMemsetAsync(d_ws, 0, (size_t)2 * N * sizeof(int), stream);

    degree_kernel<<<(E + 255) / 256, 256, 0, stream>>>(esrc, edst, odeg, ideg, E);
    scan_kernel<<<1, 1024, 0, stream>>>(ideg, odeg, offs, rs_odeg, N);
    bucket_kernel<<<(E + 255) / 256, 256, 0, stream>>>(esrc, edst, offs, sorted_src, E);
    gather_kernel<<<(N + 3) / 4, 256, 0, stream>>>(x, sorted_src, offs, rs_odeg, ideg, out, N);
    ffn_kernel<<<(N + 63) / 64, 64, 0, stream>>>(out, w1, b1, w2, b2, N);
}

// Round 3
// 258.623 us; speedup vs baseline: 1.5178x; 1.4617x over previous
//
#include <hip/hip_runtime.h>
#include <hip/hip_bf16.h>
#include <math.h>

#define DD 64

__device__ __forceinline__ int wave_incl_scan(int v, int lane) {
    #pragma unroll
    for (int d = 1; d < 64; d <<= 1) {
        int u = __shfl_up(v, d, 64);
        if (lane >= d) v += u;
    }
    return v;
}

// ---------------- degree kernel ----------------
__global__ __launch_bounds__(256) void degree_kernel(
    const int* __restrict__ src, const int* __restrict__ dst,
    int* __restrict__ odeg, int* __restrict__ ideg, int E)
{
    int e = blockIdx.x * 256 + threadIdx.x;
    if (e < E) {
        atomicAdd(&odeg[src[e]], 1);
        atomicAdd(&ideg[dst[e]], 1);
    }
}

// ---------------- hierarchical scan ----------------
// K1: per-block (256 elems) exclusive scan of ideg -> offs, block totals -> bsum
//     also rs_odeg = rsqrt(odeg)
__global__ __launch_bounds__(256) void scan1_kernel(
    const int* __restrict__ ideg, const int* __restrict__ odeg,
    int* __restrict__ offs, float* __restrict__ rs_odeg,
    int* __restrict__ bsum, int n)
{
    int t = threadIdx.x, lane = t & 63, wid = t >> 6;
    int i = blockIdx.x * 256 + t;
    int v = (i < n) ? ideg[i] : 0;
    int sv = wave_incl_scan(v, lane);
    __shared__ int ws[4], wso[4];
    if (lane == 63) ws[wid] = sv;
    __syncthreads();
    if (t == 0) {
        int a = 0;
        for (int w = 0; w < 4; ++w) { wso[w] = a; a += ws[w]; }
        bsum[blockIdx.x] = a;
    }
    __syncthreads();
    if (i < n) {
        offs[i] = sv - v + wso[wid];
        rs_odeg[i] = rsqrtf((float)odeg[i]);  // inf only for never-src nodes (never read)
    }
}

// K2: single block scans bsum[nb] (nb <= 256) exclusive, in place
__global__ __launch_bounds__(256) void scan2_kernel(int* __restrict__ bsum, int nb)
{
    int t = threadIdx.x, lane = t & 63, wid = t >> 6;
    int v = (t < nb) ? bsum[t] : 0;
    int sv = wave_incl_scan(v, lane);
    __shared__ int ws[4], wso[4];
    if (lane == 63) ws[wid] = sv;
    __syncthreads();
    if (t == 0) {
        int a = 0;
        for (int w = 0; w < 4; ++w) { wso[w] = a; a += ws[w]; }
    }
    __syncthreads();
    if (t < nb) bsum[t] = sv - v + wso[wid];
}

// K3: add block offsets
__global__ __launch_bounds__(256) void scan3_kernel(
    int* __restrict__ offs, const int* __restrict__ bsum, int n)
{
    int i = blockIdx.x * 256 + threadIdx.x;
    if (i < n) offs[i] += bsum[blockIdx.x];
}

// ---------------- bucket-fill ----------------
// offs[d] = exclusive start; atomic post-inc turns it into inclusive end
__global__ __launch_bounds__(256) void bucket_kernel(
    const int* __restrict__ src, const int* __restrict__ dst,
    int* __restrict__ offs, int* __restrict__ sorted_src, int E)
{
    int e = blockIdx.x * 256 + threadIdx.x;
    if (e < E) {
        int pos = atomicAdd(&offs[dst[e]], 1);
        sorted_src[pos] = src[e];
    }
}

// ---------------- gather ----------------
// one wave per dst node. Lane = (sub, c4): sub=lane>>4 picks 1 of 4 edges per
// chunk, c4=lane&15 picks a float4 of the feature row. Edge (src, weight)
// pairs prefetched into wave-local LDS (no barrier needed within a wave).
__global__ __launch_bounds__(256) void gather_kernel(
    const float* __restrict__ x,
    const int* __restrict__ sorted_src,
    const int* __restrict__ offs,
    const float* __restrict__ rs_odeg,
    const int* __restrict__ ideg,
    float* __restrict__ out, int N)
{
    __shared__ int   sS[4][68];
    __shared__ float sW[4][68];
    int t = threadIdx.x, lane = t & 63, wid = t >> 6;
    int sub = lane >> 4, c4 = lane & 15;
    int d = blockIdx.x * 4 + wid;
    if (d >= N) return;

    int end = offs[d];
    int beg = (d == 0) ? 0 : offs[d - 1];
    int cnt = end - beg;
    int capped = min(cnt, 64);

    int s_l = 0; float w_l = 0.0f;
    if (lane < capped) {
        s_l = sorted_src[beg + lane];
        w_l = rs_odeg[s_l];
    }
    sS[wid][lane] = s_l;
    sW[wid][lane] = w_l;
    if (lane < 4) { sS[wid][64 + lane] = 0; sW[wid][64 + lane] = 0.0f; }

    float4 acc = make_float4(0.f, 0.f, 0.f, 0.f);
    for (int j = 0; j < capped; j += 4) {
        int jj = j + sub;                 // <= 66; pad entries are zero-weight
        int   s = sS[wid][jj];
        float w = sW[wid][jj];
        const float4 xv = *(const float4*)&x[(size_t)s * DD + (c4 << 2)];
        acc.x = fmaf(w, xv.x, acc.x);
        acc.y = fmaf(w, xv.y, acc.y);
        acc.z = fmaf(w, xv.z, acc.z);
        acc.w = fmaf(w, xv.w, acc.w);
    }
    // rare tail: degree > 64
    for (int j = 64 + sub; j < cnt; j += 4) {
        int s = sorted_src[beg + j];
        float w = rs_odeg[s];
        const float4 xv = *(const float4*)&x[(size_t)s * DD + (c4 << 2)];
        acc.x = fmaf(w, xv.x, acc.x);
        acc.y = fmaf(w, xv.y, acc.y);
        acc.z = fmaf(w, xv.z, acc.z);
        acc.w = fmaf(w, xv.w, acc.w);
    }
    // reduce the 4 sub-groups (xor-reduce leaves total in every lane)
    acc.x += __shfl_xor(acc.x, 16, 64); acc.x += __shfl_xor(acc.x, 32, 64);
    acc.y += __shfl_xor(acc.y, 16, 64); acc.y += __shfl_xor(acc.y, 32, 64);
    acc.z += __shfl_xor(acc.z, 16, 64); acc.z += __shfl_xor(acc.z, 32, 64);
    acc.w += __shfl_xor(acc.w, 16, 64); acc.w += __shfl_xor(acc.w, 32, 64);

    float nd = (cnt > 0) ? rsqrtf((float)ideg[d]) : 0.0f;
    if (sub == 0) {
        acc.x *= nd; acc.y *= nd; acc.z *= nd; acc.w *= nd;
        *(float4*)&out[(size_t)d * DD + (c4 << 2)] = acc;
    }
}

// ---------------- FFN ----------------
// 256 threads, 64 rows/block; thread = (row = t>>2, 16-col chunk = (t&3)*16).
// Weights in LDS (float4 reads, 2-way bank alias = free). Row tile stride 68
// (b128-aligned; row-broadcast reads are 2-way = free). One barrier after
// staging; GEMM1->GELU->GEMM2 touch only the own wave's rows (lockstep-safe).
__global__ __launch_bounds__(256) void ffn_kernel(
    float* __restrict__ io,
    const float* __restrict__ w1, const float* __restrict__ b1,
    const float* __restrict__ w2, const float* __restrict__ b2, int n)
{
    __shared__ float sW1[4096];
    __shared__ float sW2[4096];
    __shared__ float sT[64 * 68];

    int t = threadIdx.x;
    int row0 = blockIdx.x * 64;

    const float4* w1v = (const float4*)w1;
    const float4* w2v = (const float4*)w2;
    #pragma unroll
    for (int q = 0; q < 4; ++q) {
        ((float4*)sW1)[t + q * 256] = w1v[t + q * 256];
        ((float4*)sW2)[t + q * 256] = w2v[t + q * 256];
    }
    #pragma unroll
    for (int q = 0; q < 4; ++q) {
        int idx4 = t + q * 256;          // float4 index in 64x64 tile
        int r = idx4 >> 4;
        int c = (idx4 & 15) << 2;
        int gr = row0 + r;
        float4 v = (gr < n) ? ((const float4*)io)[((size_t)gr * DD + c) >> 2]
                            : make_float4(0.f, 0.f, 0.f, 0.f);
        *(float4*)&sT[r * 68 + c] = v;
    }
    __syncthreads();

    int r = t >> 2;
    int cb = (t & 3) << 4;

    float acc[16];
    #pragma unroll
    for (int j = 0; j < 16; ++j) acc[j] = b1[cb + j];
    #pragma unroll 4
    for (int k = 0; k < 64; ++k) {
        float rv = sT[r * 68 + k];
        #pragma unroll
        for (int q = 0; q < 4; ++q) {
            float4 w = *(const float4*)&sW1[k * 64 + cb + (q << 2)];
            acc[q*4+0] = fmaf(rv, w.x, acc[q*4+0]);
            acc[q*4+1] = fmaf(rv, w.y, acc[q*4+1]);
            acc[q*4+2] = fmaf(rv, w.z, acc[q*4+2]);
            acc[q*4+3] = fmaf(rv, w.w, acc[q*4+3]);
        }
    }
    // exact GELU, write h back into own row (wave-local, program-ordered)
    #pragma unroll
    for (int j = 0; j < 16; ++j) {
        float v = acc[j];
        acc[j] = 0.5f * v * (1.0f + erff(v * 0.70710678118654752f));
    }
    #pragma unroll
    for (int q = 0; q < 4; ++q)
        *(float4*)&sT[r * 68 + cb + (q << 2)] =
            make_float4(acc[q*4+0], acc[q*4+1], acc[q*4+2], acc[q*4+3]);

    #pragma unroll
    for (int j = 0; j < 16; ++j) acc[j] = b2[cb + j];
    #pragma unroll 4
    for (int k = 0; k < 64; ++k) {
        float hv = sT[r * 68 + k];
        #pragma unroll
        for (int q = 0; q < 4; ++q) {
            float4 w = *(const float4*)&sW2[k * 64 + cb + (q << 2)];
            acc[q*4+0] = fmaf(hv, w.x, acc[q*4+0]);
            acc[q*4+1] = fmaf(hv, w.y, acc[q*4+1]);
            acc[q*4+2] = fmaf(hv, w.z, acc[q*4+2]);
            acc[q*4+3] = fmaf(hv, w.w, acc[q*4+3]);
        }
    }
    int gr = row0 + r;
    if (gr < n) {
        #pragma unroll
        for (int q = 0; q < 4; ++q)
            ((float4*)io)[((size_t)gr * DD + cb + (q << 2)) >> 2] =
                make_float4(acc[q*4+0], acc[q*4+1], acc[q*4+2], acc[q*4+3]);
    }
}

extern "C" void kernel_launch(void* const* d_in, const int* in_sizes, int n_in,
                              void* d_out, int out_size, void* d_ws, size_t ws_size,
                              hipStream_t stream)
{
    const float* x    = (const float*)d_in[0];
    const int*   esrc = (const int*)d_in[1];
    const int*   edst = (const int*)d_in[2];
    const float* w1   = (const float*)d_in[3];
    const float* b1   = (const float*)d_in[4];
    const float* w2   = (const float*)d_in[5];
    const float* b2   = (const float*)d_in[6];
    float* out = (float*)d_out;

    int N = in_sizes[0] / DD;   // 50000
    int E = in_sizes[1];        // 800000
    int nb = (N + 255) / 256;   // 196

    int*   ideg       = (int*)d_ws;            // N
    int*   odeg       = ideg + N;              // N
    int*   offs       = odeg + N;              // N
    float* rs_odeg    = (float*)(offs + N);    // N
    int*   bsum       = (int*)(rs_odeg + N);   // 256
    int*   sorted_src = bsum + 256;            // E

    hipMemsetAsync(d_ws, 0, (size_t)2 * N * sizeof(int), stream);

    degree_kernel<<<(E + 255) / 256, 256, 0, stream>>>(esrc, edst, odeg, ideg, E);
    scan1_kernel<<<nb, 256, 0, stream>>>(ideg, odeg, offs, rs_odeg, bsum, N);
    scan2_kernel<<<1, 256, 0, stream>>>(bsum, nb);
    scan3_kernel<<<nb, 256, 0, stream>>>(offs, bsum, N);
    bucket_kernel<<<(E + 255) / 256, 256, 0, stream>>>(esrc, edst, offs, sorted_src, E);
    gather_kernel<<<(N + 3) / 4, 256, 0, stream>>>(x, sorted_src, offs, rs_odeg, ideg, out, N);
    ffn_kernel<<<(N + 63) / 64, 256, 0, stream>>>(out, w1, b1, w2, b2, N);
}